// Round 17
// baseline (1350.890 us; speedup 1.0000x reference)
//
#include <hip/hip_runtime.h>

namespace {
constexpr int NB = 16;    // batch
constexpr int NP = 50;    // P nodes
constexpr int NM = 512;   // M
constexpr int NN = 1024;  // N
constexpr int NK = 20;    // scan steps
constexpr long ASZ = (long)NP * NM * NN;   // 26,214,400
constexpr long YSZ = (long)NB * NP * NN;   // 819,200
}

typedef __attribute__((ext_vector_type(8))) short bf16x8;
typedef __attribute__((ext_vector_type(4))) float f32x4;

__device__ __forceinline__ float lrelu(float x){ return x > 0.f ? x : 0.01f*x; }
__device__ __forceinline__ float bfu(unsigned short x){
  unsigned v = ((unsigned)x) << 16;
  return __builtin_bit_cast(float, v);
}
__device__ __forceinline__ unsigned short f2bf(float f){   // RNE f32->bf16
  unsigned u = __builtin_bit_cast(unsigned, f);
  u += 0x7fffu + ((u >> 16) & 1u);
  return (unsigned short)(u >> 16);
}
// tiled AtA element offset: [ntile=n>>4][ks=k>>5][lr=n&15][kg=(k>>3)&3][e=k&7]
__device__ __forceinline__ long toff(int n, int kk){
  return (long)(n>>4)*16384 + (long)(kk>>5)*512 + (long)((n&15)*32 + ((kk>>3)&3)*8 + (kk&7));
}

// ---------------- A (f32) -> abfT (transposed bf16 [p][n][m]) ----------------
__global__ __launch_bounds__(256) void k_prep(const float* __restrict__ A,
                      unsigned short* __restrict__ abfT){
  const int p = blockIdx.x, mt = blockIdx.y, nt = blockIdx.z;
  const int tid = threadIdx.x;
  __shared__ unsigned short tile[64][72];
  const int m0 = mt*64, n0 = nt*64;
  {
    int r = tid>>2, cs = (tid&3)*16;
    const float* src = A + ((long)p*NM + m0 + r)*NN + n0 + cs;
    unsigned short tmp[16];
    #pragma unroll
    for (int q=0;q<16;q+=4){
      float4 v = *(const float4*)(src+q);
      tmp[q+0]=f2bf(v.x); tmp[q+1]=f2bf(v.y); tmp[q+2]=f2bf(v.z); tmp[q+3]=f2bf(v.w);
    }
    #pragma unroll
    for (int q=0;q<16;q++) tile[r][cs+q] = tmp[q];
  }
  __syncthreads();
  {
    int r = tid>>2, cs = (tid&3)*16;   // r = n-offset, cs = m-offset
    unsigned short* dst = abfT + ((long)p*NN + n0 + r)*NM + m0 + cs;
    unsigned short tmp[16];
    #pragma unroll
    for (int q=0;q<16;q++) tmp[q] = tile[cs+q][r];
    #pragma unroll
    for (int q=0;q<16;q+=8) *(uint4*)(dst+q) = *(const uint4*)&tmp[q];
  }
}

// ---------------- scan-state init: ybf only (bf16 state carrier) ----------------
__global__ void k_init(const float* __restrict__ y0, unsigned short* __restrict__ ybf, int n){
  int e = (blockIdx.x*blockDim.x + threadIdx.x)*4;
  if (e >= n) return;
  float4 a = *(const float4*)(y0+e);
  ushort4 o; o.x=f2bf(a.x); o.y=f2bf(a.y); o.z=f2bf(a.z); o.w=f2bf(a.w);
  *(ushort4*)(ybf+e) = o;
}

// ---------------- w0 = u0*snb - atb ; e0 = w0 + d0*rho_0 ----------------
__global__ __launch_bounds__(256) void k_e0(const float* __restrict__ u0,
      const float* __restrict__ d0, const float* __restrict__ atb,
      const float* __restrict__ snbg, const float* __restrict__ hypg,
      float* __restrict__ w, float* __restrict__ e){
  long i = ((long)blockIdx.x*256 + threadIdx.x)*4;
  if (i >= YSZ) return;
  long bp = i >> 10;          // b*NP+p
  int b = (int)(bp/NP), p = (int)(bp%NP);
  float sp = snbg[b*NP+p], rho = hypg[b*80 + 2];
  float4 uv = *(const float4*)(u0+i);
  float4 dv = *(const float4*)(d0+i);
  float4 av = *(const float4*)(atb+i);
  float4 wv, ev;
  wv.x = uv.x*sp - av.x; wv.y = uv.y*sp - av.y;
  wv.z = uv.z*sp - av.z; wv.w = uv.w*sp - av.w;
  ev.x = wv.x + dv.x*rho; ev.y = wv.y + dv.y*rho;
  ev.z = wv.z + dv.z*rho; ev.w = wv.w + dv.w*rho;
  *(float4*)(w+i) = wv;
  *(float4*)(e+i) = ev;
}

// ================= role bodies (shared by merged kernel) =================

// ---- encoder GEMM body: float4 W stream, acc[16] float4 ----
__device__ __forceinline__ void enc_body(const float* __restrict__ X, const float* __restrict__ W,
                           float* __restrict__ part, int fi, int fo, int ichunk, int actin,
                           int bx, int c, int tid, char* smem){
  float (*xs)[16] = (float(*)[16])smem;   // [64][16]
  const int o0 = (bx*256 + tid)*4;
  const bool ok = o0 < fo;   // fo multiple of 4
  float4 acc[16];
  #pragma unroll
  for (int b=0;b<16;b++){ acc[b].x=0.f; acc[b].y=0.f; acc[b].z=0.f; acc[b].w=0.f; }
  const long ibase = (long)c*ichunk;
  const int xb = tid&15, xio = (tid>>4)*4;
  for (int s=0; s<ichunk; s+=64){
    float4 v = *(const float4*)(X + (long)xb*fi + ibase + s + xio);
    if (actin){ v.x=lrelu(v.x); v.y=lrelu(v.y); v.z=lrelu(v.z); v.w=lrelu(v.w); }
    __syncthreads();
    xs[xio+0][xb]=v.x; xs[xio+1][xb]=v.y; xs[xio+2][xb]=v.z; xs[xio+3][xb]=v.w;
    __syncthreads();
    const float* wp = W + (ibase+s)*fo + o0;
    #pragma unroll 4
    for (int i=0;i<64;i++){
      float4 w;
      if (ok) w = *(const float4*)(wp + (long)i*fo);
      else { w.x=0.f; w.y=0.f; w.z=0.f; w.w=0.f; }
      #pragma unroll
      for (int b2=0;b2<16;b2+=4){
        float4 x4 = *(const float4*)&xs[i][b2];
        acc[b2+0].x += w.x*x4.x; acc[b2+0].y += w.y*x4.x; acc[b2+0].z += w.z*x4.x; acc[b2+0].w += w.w*x4.x;
        acc[b2+1].x += w.x*x4.y; acc[b2+1].y += w.y*x4.y; acc[b2+1].z += w.z*x4.y; acc[b2+1].w += w.w*x4.y;
        acc[b2+2].x += w.x*x4.z; acc[b2+2].y += w.y*x4.z; acc[b2+2].z += w.z*x4.z; acc[b2+2].w += w.w*x4.z;
        acc[b2+3].x += w.x*x4.w; acc[b2+3].y += w.y*x4.w; acc[b2+3].z += w.z*x4.w; acc[b2+3].w += w.w*x4.w;
      }
    }
  }
  if (ok){
    float* pp = part + ((long)c*16)*fo + o0;
    #pragma unroll
    for (int b=0;b<16;b++) *(float4*)(pp + (long)b*fo) = acc[b];
  }
}

// ---- AtA body (tile-pair bi<=bj), bf16 out in TILED layout ----
__device__ __forceinline__ void ata_body(const unsigned short* __restrict__ abfT,
                      unsigned short* __restrict__ ata, int yy_in, int p, int tid, char* smem){
  unsigned short (*pa)[72] = (unsigned short(*)[72])smem;            // [128][72]
  unsigned short (*pb)[72] = (unsigned short(*)[72])(smem + 18432);  // [128][72]
  int yy = yy_in, bi = 0;
  while (yy >= 8 - bi){ yy -= 8 - bi; bi++; }
  const int bj = bi + yy;
  const int i0 = bi*128, j0 = bj*128;
  const int wave = tid>>6, lane = tid&63;
  const int lr = lane&15, kg = lane>>4;
  f32x4 acc[2][8];
  #pragma unroll
  for (int ti=0;ti<2;ti++)
    #pragma unroll
    for (int tj=0;tj<8;tj++) acc[ti][tj] = (f32x4){0.f,0.f,0.f,0.f};
  const unsigned short* Abase = abfT + (long)p*NN*NM;
  for (int mc=0; mc<NM; mc+=64){
    __syncthreads();
    {
      int r = tid>>1, c0 = (tid&1)*32;
      const unsigned short* sa = Abase + (long)(i0 + r)*NM + mc + c0;
      const unsigned short* sb = Abase + (long)(j0 + r)*NM + mc + c0;
      #pragma unroll
      for (int q=0;q<32;q+=8){
        *(uint4*)&pa[r][c0+q] = *(const uint4*)(sa+q);
        *(uint4*)&pb[r][c0+q] = *(const uint4*)(sb+q);
      }
    }
    __syncthreads();
    #pragma unroll
    for (int ks=0; ks<2; ks++){
      bf16x8 av0 = *(const bf16x8*)&pa[wave*32      + lr][ks*32 + kg*8];
      bf16x8 av1 = *(const bf16x8*)&pa[wave*32 + 16 + lr][ks*32 + kg*8];
      #pragma unroll
      for (int tj=0;tj<8;tj++){
        bf16x8 bv = *(const bf16x8*)&pb[tj*16 + lr][ks*32 + kg*8];
        acc[0][tj] = __builtin_amdgcn_mfma_f32_16x16x32_bf16(av0, bv, acc[0][tj], 0,0,0);
        acc[1][tj] = __builtin_amdgcn_mfma_f32_16x16x32_bf16(av1, bv, acc[1][tj], 0,0,0);
      }
    }
  }
  const long pbase = (long)p << 20;
  #pragma unroll
  for (int ti=0; ti<2; ti++){
    const int ib = i0 + wave*32 + ti*16;
    #pragma unroll
    for (int tj=0; tj<8; tj++){
      const int jb = j0 + tj*16;
      unsigned short w[4];
      #pragma unroll
      for (int r=0;r<4;r++) w[r] = f2bf(acc[ti][tj][r]);
      #pragma unroll
      for (int r=0;r<4;r++)
        ata[pbase + toff(ib + kg*4 + r, jb + lr)] = w[r];
      if (bi != bj){
        #pragma unroll
        for (int r=0;r<4;r++)
          ata[pbase + toff(jb + lr, ib + kg*4 + r)] = w[r];
      }
    }
  }
}

// ---- Atb body: atb[b,p,n] = sum_m A[p,m,n]*b[b,p,m] (f32 src) ----
__device__ __forceinline__ void atb_body(const unsigned short* __restrict__ abfT,
                      const float* __restrict__ src, float* __restrict__ z,
                      int p, int gy, int tid, char* smem){
  unsigned short (*tlds)[520] = (unsigned short(*)[520])smem;   // [16][520]
  const int wave = tid>>6, lane = tid&63;
  {
    int b = tid>>4, c0 = (tid&15)*8;
    const float* tr = src + ((long)b*NP + p)*NM;
    #pragma unroll
    for (int it=0; it<4; it++){
      float4 lo = *(const float4*)(tr + it*128 + c0);
      float4 hi = *(const float4*)(tr + it*128 + c0 + 4);
      unsigned short w[8];
      w[0]=f2bf(lo.x); w[1]=f2bf(lo.y); w[2]=f2bf(lo.z); w[3]=f2bf(lo.w);
      w[4]=f2bf(hi.x); w[5]=f2bf(hi.y); w[6]=f2bf(hi.z); w[7]=f2bf(hi.w);
      *(uint4*)&tlds[b][it*128 + c0] = *(const uint4*)w;
    }
  }
  __syncthreads();
  const int lr = lane&15, kg = lane>>4;
  const int nt0 = gy*4 + wave;
  const int n0 = nt0*16, n1 = (nt0+32)*16;
  const unsigned short* b0 = abfT + ((long)p*NN + n0 + lr)*NM + kg*8;
  const unsigned short* b1 = abfT + ((long)p*NN + n1 + lr)*NM + kg*8;
  const unsigned short* tp = &tlds[lr][kg*8];
  f32x4 acc0a={0.f,0.f,0.f,0.f}, acc0b={0.f,0.f,0.f,0.f};
  f32x4 acc1a={0.f,0.f,0.f,0.f}, acc1b={0.f,0.f,0.f,0.f};
  #pragma unroll 4
  for (int ks=0; ks<16; ks+=2){
    bf16x8 t0 = *(const bf16x8*)(tp + ks*32);
    bf16x8 t1 = *(const bf16x8*)(tp + ks*32 + 32);
    bf16x8 b00 = *(const bf16x8*)(b0 + (long)ks*32);
    bf16x8 b01 = *(const bf16x8*)(b0 + (long)ks*32 + 32);
    bf16x8 b10 = *(const bf16x8*)(b1 + (long)ks*32);
    bf16x8 b11 = *(const bf16x8*)(b1 + (long)ks*32 + 32);
    acc0a = __builtin_amdgcn_mfma_f32_16x16x32_bf16(t0, b00, acc0a, 0, 0, 0);
    acc1a = __builtin_amdgcn_mfma_f32_16x16x32_bf16(t0, b10, acc1a, 0, 0, 0);
    acc0b = __builtin_amdgcn_mfma_f32_16x16x32_bf16(t1, b01, acc0b, 0, 0, 0);
    acc1b = __builtin_amdgcn_mfma_f32_16x16x32_bf16(t1, b11, acc1b, 0, 0, 0);
  }
  f32x4 acc0 = acc0a + acc0b;
  f32x4 acc1 = acc1a + acc1b;
  #pragma unroll
  for (int r=0;r<4;r++){
    int bb = kg*4 + r;
    z[((long)bb*NP + p)*NN + n0 + lr] = acc0[r];
    z[((long)bb*NP + p)*NN + n1 + lr] = acc1[r];
  }
}

// ---- graph body (256 threads): adjacency, delta operator, src counts ----
__device__ __forceinline__ void graph_body(const int* __restrict__ ei, float* __restrict__ adjg,
                      float* __restrict__ dmg, float* __restrict__ snbg, int b, int tid, char* smem){
  float* adj = (float*)smem;          // 2500
  float* dm  = adj + 2500;            // 2500
  float* deg = dm + 2500;             // 50
  float* dinv= deg + 50;              // 50
  float* snb = dinv + 50;             // 50
  for (int i=tid;i<2500;i+=256){ adj[i]=0.f; dm[i]=0.f; }
  if (tid<50){ deg[tid]=0.f; snb[tid]=0.f; }
  __syncthreads();
  const int* e = ei + b*800;
  for (int k=tid;k<400;k+=256){
    atomicAdd(&deg[e[400+k]], 1.f);
    atomicAdd(&snb[e[k]], 1.f);
  }
  __syncthreads();
  if (tid<50) dinv[tid] = 1.f / sqrtf(deg[tid] + 1.f);
  __syncthreads();
  for (int k=tid;k<400;k+=256){
    int s = e[k], d = e[400+k];
    atomicAdd(&adj[d*50+s], dinv[s]*dinv[d]);
    atomicAdd(&dm[s*50+s],  1.f); atomicAdd(&dm[s*50+d], -1.f);
    atomicAdd(&dm[d*50+d],  1.f); atomicAdd(&dm[d*50+s], -1.f);
  }
  __syncthreads();
  if (tid<50) adj[tid*50+tid] += dinv[tid]*dinv[tid];
  __syncthreads();
  for (int i=tid;i<2500;i+=256){ adjg[b*2500+i]=adj[i]; dmg[b*2500+i]=dm[i]; }
  if (tid<50) snbg[b*50+tid]=snb[tid];
}

// ---------------- merged (roles interleaved mod 13): enc-L1 ∥ AtA ∥ Atb ∥ graph ----------------
__global__ __launch_bounds__(256) void k_big(const unsigned short* __restrict__ abfT,
      unsigned short* __restrict__ ata, const float* __restrict__ bin,
      const float* __restrict__ We1, float* __restrict__ part,
      float* __restrict__ atb, const int* __restrict__ ei,
      float* __restrict__ adjg, float* __restrict__ dmg, float* __restrict__ snbg){
  __shared__ __align__(16) char smem[36864];
  const int bid = blockIdx.x, tid = threadIdx.x;
  if (bid < 2600){
    const int g = bid/13, r = bid%13;
    if (r < 2){                       // 400 enc blocks
      int idx = g*2 + r;
      enc_body(bin, We1, part, 25600, 3200, 256, 0, idx & 3, idx >> 2, tid, smem);
    } else if (r < 11){               // 1800 ata blocks
      int a = g*9 + (r-2);
      ata_body(abfT, ata, a % 36, a / 36, tid, smem);
    } else {                          // 400 atb blocks
      int a = g*2 + (r-11);
      atb_body(abfT, bin, atb, a >> 3, a & 7, tid, smem);
    }
  } else {
    graph_body(ei, adjg, dmg, snbg, bid - 2600, tid, smem);
  }
}

// ---------------- standalone encoder GEMM (L2/L3) ----------------
__global__ __launch_bounds__(256) void k_enc2(const float* __restrict__ X, const float* __restrict__ W,
                           float* __restrict__ part, int fi, int fo, int ichunk, int actin){
  __shared__ __align__(16) char smem[4096];
  enc_body(X, W, part, fi, fo, ichunk, actin, blockIdx.x, blockIdx.y, threadIdx.x, smem);
}

__global__ void k_enc_reduce(const float* __restrict__ part, const float* __restrict__ bias,
                             float* __restrict__ out, int fo, int nchunk){
  int i = blockIdx.x*256 + threadIdx.x;
  if (i >= 16*fo) return;
  int o = i % fo;
  float s = bias[o];
  for (int c=0;c<nchunk;c++) s += part[(long)c*16*fo + i];
  out[i] = s;
}

// ---------------- fused GCN x2 + head ----------------
__global__ __launch_bounds__(256) void k_gnn(const float* __restrict__ h3,
     const float* __restrict__ Wc1, const float* __restrict__ bc1,
     const float* __restrict__ Wc2, const float* __restrict__ bc2,
     const float* __restrict__ Wf1, const float* __restrict__ bf1,
     const float* __restrict__ Wf2, const float* __restrict__ bf2,
     const float* __restrict__ maxp, const float* __restrict__ adjg,
     float* __restrict__ hypg){
  const int b = blockIdx.x, tid = threadIdx.x;
  __shared__ float adj[2500];
  __shared__ float bufA[6400];
  __shared__ float bufB[6400];
  __shared__ float xm[128], hv1[64], raw[80];
  for (int i=tid;i<2500;i+=256) adj[i] = adjg[b*2500+i];

  const int j = tid & 127, nh = tid >> 7;
  float acc[25];
  #pragma unroll
  for (int q=0;q<25;q++) acc[q]=0.f;
  for (int ic=0; ic<4; ic++){
    __syncthreads();
    for (int e=tid; e<800; e+=256){
      int n = e>>4, seg = (e&15)*4;
      *(float4*)&bufB[n*64+seg] = *(const float4*)(h3 + (long)b*12800 + n*256 + ic*64 + seg);
    }
    __syncthreads();
    for (int i=0;i<64;i+=4){
      float w0 = Wc1[(long)(ic*64+i+0)*128 + j];
      float w1 = Wc1[(long)(ic*64+i+1)*128 + j];
      float w2 = Wc1[(long)(ic*64+i+2)*128 + j];
      float w3 = Wc1[(long)(ic*64+i+3)*128 + j];
      #pragma unroll
      for (int q=0;q<25;q++){
        float4 xv = *(const float4*)&bufB[(nh*25+q)*64 + i];
        acc[q] += xv.x*w0 + xv.y*w1 + xv.z*w2 + xv.w*w3;
      }
    }
  }
  __syncthreads();
  #pragma unroll
  for (int q=0;q<25;q++) bufA[(nh*25+q)*128 + j] = acc[q];
  __syncthreads();
  {
    float a2[25];
    float bv = bc1[j];
    #pragma unroll
    for (int q=0;q<25;q++) a2[q]=bv;
    for (int qq=0; qq<50; qq++){
      float hvv = bufA[qq*128 + j];
      #pragma unroll
      for (int q=0;q<25;q++) a2[q] += adj[(nh*25+q)*50 + qq]*hvv;
    }
    __syncthreads();
    #pragma unroll
    for (int q=0;q<25;q++) bufB[(nh*25+q)*128 + j] = lrelu(a2[q]);
  }
  __syncthreads();
  {
    float a2[25];
    #pragma unroll
    for (int q=0;q<25;q++) a2[q]=0.f;
    for (int i=0;i<128;i+=4){
      float w0 = Wc2[(long)(i+0)*128 + j];
      float w1 = Wc2[(long)(i+1)*128 + j];
      float w2 = Wc2[(long)(i+2)*128 + j];
      float w3 = Wc2[(long)(i+3)*128 + j];
      #pragma unroll
      for (int q=0;q<25;q++){
        float4 xv = *(const float4*)&bufB[(nh*25+q)*128 + i];
        a2[q] += xv.x*w0 + xv.y*w1 + xv.z*w2 + xv.w*w3;
      }
    }
    __syncthreads();
    #pragma unroll
    for (int q=0;q<25;q++) bufA[(nh*25+q)*128 + j] = a2[q];
  }
  __syncthreads();
  {
    float a2[25];
    float bv = bc2[j];
    #pragma unroll
    for (int q=0;q<25;q++) a2[q]=bv;
    for (int qq=0; qq<50; qq++){
      float hvv = bufA[qq*128 + j];
      #pragma unroll
      for (int q=0;q<25;q++) a2[q] += adj[(nh*25+q)*50 + qq]*hvv;
    }
    __syncthreads();
    #pragma unroll
    for (int q=0;q<25;q++) bufB[(nh*25+q)*128 + j] = lrelu(a2[q]);
  }
  __syncthreads();
  if (tid < 128){
    float s = 0.f;
    for (int n=0;n<50;n++) s += bufB[n*128 + tid];
    xm[tid] = s * (1.f/50.f);
  }
  __syncthreads();
  if (tid < 64){
    float s = bf1[tid];
    for (int i=0;i<128;i++) s += xm[i]*Wf1[i*64 + tid];
    hv1[tid] = lrelu(s);
  }
  __syncthreads();
  if (tid < 80){
    float s = bf2[tid];
    for (int i=0;i<64;i++) s += hv1[i]*Wf2[i*80 + tid];
    raw[tid] = s;
  }
  __syncthreads();
  if (tid < 4){
    float c = 0.f;
    for (int k=0;k<20;k++){
      c += raw[k*4 + tid];
      hypg[b*80 + k*4 + tid] = maxp[tid] / (1.f + expf(-c));
    }
  }
}

// ---------------- scan: split-K z = AtA[p] @ y + fused y-update (bf16 state carrier) ----------------
__global__ __launch_bounds__(256, 6) void k_z(const unsigned short* __restrict__ ata,
      const unsigned short* __restrict__ ybin, const float* __restrict__ ebuf,
      const float* __restrict__ hypg, int k,
      unsigned short* __restrict__ ybout, float* __restrict__ yout){
  const int p = blockIdx.x;
  const int tid = threadIdx.x, wave = tid>>6, lane = tid&63;
  const int lr = lane&15, kg = lane>>4;
  const int tl = wave>>1;                        // tile local 0..1
  const int kh = wave&1;                         // K-half
  const int t  = blockIdx.y*2 + tl;              // n-tile 0..63
  const int n0 = t*16;
  __shared__ float part[2][16][17];
  const unsigned short* bp  = ata + ((long)p<<20) + (long)t*16384 + kh*8192 + lr*32 + kg*8;
  const unsigned short* ypg = ybin + ((long)lr*NP + p)*NN + kh*512 + kg*8;

  // epilogue operand preload (low-half waves only; overlaps MFMA)
  float yv4[4], e4[4];
  float4 hp4[4];
  if (kh == 0){
    #pragma unroll
    for (int r=0;r<4;r++){
      const int b = kg*4 + r;
      const long idx = ((long)b*NP + p)*NN + n0 + lr;
      yv4[r] = bfu(ybin[idx]); e4[r] = ebuf[idx];
      hp4[r] = *(const float4*)(hypg + b*80 + k*4);
    }
  }

  f32x4 a0={0.f,0.f,0.f,0.f}, a1={0.f,0.f,0.f,0.f}, a2={0.f,0.f,0.f,0.f}, a3={0.f,0.f,0.f,0.f};
  #pragma unroll
  for (int i=0;i<4;i++){
    bf16x8 b0 = *(const bf16x8*)(bp + (i*4+0)*512);
    bf16x8 b1 = *(const bf16x8*)(bp + (i*4+1)*512);
    bf16x8 b2 = *(const bf16x8*)(bp + (i*4+2)*512);
    bf16x8 b3 = *(const bf16x8*)(bp + (i*4+3)*512);
    bf16x8 q0 = *(const bf16x8*)(ypg + (i*4+0)*32);
    bf16x8 q1 = *(const bf16x8*)(ypg + (i*4+1)*32);
    bf16x8 q2 = *(const bf16x8*)(ypg + (i*4+2)*32);
    bf16x8 q3 = *(const bf16x8*)(ypg + (i*4+3)*32);
    a0 = __builtin_amdgcn_mfma_f32_16x16x32_bf16(q0, b0, a0, 0,0,0);
    a1 = __builtin_amdgcn_mfma_f32_16x16x32_bf16(q1, b1, a1, 0,0,0);
    a2 = __builtin_amdgcn_mfma_f32_16x16x32_bf16(q2, b2, a2, 0,0,0);
    a3 = __builtin_amdgcn_mfma_f32_16x16x32_bf16(q3, b3, a3, 0,0,0);
  }
  f32x4 zh = (a0 + a1) + (a2 + a3);
  if (kh == 1){
    #pragma unroll
    for (int r=0;r<4;r++) part[tl][kg*4+r][lr] = zh[r];
  }
  __syncthreads();
  if (kh == 0){
    #pragma unroll
    for (int r=0;r<4;r++){
      const int b = kg*4 + r;
      const long idx = ((long)b*NP + p)*NN + n0 + lr;
      float z = zh[r] + part[tl][kg*4+r][lr];
      float yv = yv4[r];
      float g = z + ((yv>0.f)?1.f:((yv<0.f)?-1.f:0.f))*hp4[r].y + e4[r];
      float ynv = yv - hp4[r].x*g;
      ybout[idx] = f2bf(ynv); yout[(long)k*YSZ + idx] = ynv;
    }
  }
}

// ---------------- scan: dl = Dm @ y_{k+1} (bf16) ; w += dl*eta*snb ; e = w + dl*rho_{k+1} ----------------
__global__ __launch_bounds__(256) void k_dm(const float* __restrict__ dmg,
      const float* __restrict__ snbg, const float* __restrict__ hypg, int k,
      const unsigned short* __restrict__ ybf, float* __restrict__ w, float* __restrict__ e){
  const int b = blockIdx.x, n0 = blockIdx.y*64, tid = threadIdx.x;
  __shared__ float ys[50][64];
  __shared__ float dms[2500];
  for (int i=tid;i<2500;i+=256) dms[i] = dmg[b*2500+i];
  for (int i=tid; i<3200; i+=256){
    int p=i>>6, nn=i&63;
    ys[p][nn] = bfu(ybf[((long)b*NP+p)*NN + n0 + nn]);
  }
  __syncthreads();
  const float eta = hypg[b*80 + k*4 + 3];
  const float rhon = hypg[b*80 + (k+1)*4 + 2];
  for (int i=tid; i<3200; i+=256){
    int p=i>>6, nn=i&63;
    float s=0.f;
    #pragma unroll 10
    for (int q=0;q<NP;q++) s += dms[p*50+q]*ys[q][nn];
    long idx = ((long)b*NP+p)*NN + n0 + nn;
    float wn = w[idx] + s*eta*snbg[b*NP+p];
    w[idx] = wn;
    e[idx] = wn + s*rhon;
  }
}

extern "C" void kernel_launch(void* const* d_in, const int* in_sizes, int n_in,
                              void* d_out, int out_size, void* d_ws, size_t ws_size,
                              hipStream_t stream){
  (void)in_sizes; (void)n_in; (void)out_size; (void)ws_size;
  const float* bin = (const float*)d_in[0];
  const float* A   = (const float*)d_in[1];
  const int*   ei  = (const int*)d_in[2];
  const float* mxp = (const float*)d_in[3];
  const float* We1 = (const float*)d_in[4];  const float* be1 = (const float*)d_in[5];
  const float* We2 = (const float*)d_in[6];  const float* be2 = (const float*)d_in[7];
  const float* We3 = (const float*)d_in[8];  const float* be3 = (const float*)d_in[9];
  const float* Wc1 = (const float*)d_in[10]; const float* bc1 = (const float*)d_in[11];
  const float* Wc2 = (const float*)d_in[12]; const float* bc2 = (const float*)d_in[13];
  const float* Wf1 = (const float*)d_in[14]; const float* bf1 = (const float*)d_in[15];
  const float* Wf2 = (const float*)d_in[16]; const float* bf2 = (const float*)d_in[17];
  const float* y0  = (const float*)d_in[18];
  const float* u0  = (const float*)d_in[19];
  const float* dd0 = (const float*)d_in[20];
  float* out = (float*)d_out;

  char* cur = (char*)d_ws;
  auto alloc = [&](size_t bytes)->void*{
    void* pp = (void*)cur; cur += (bytes + 255) & ~(size_t)255; return pp;
  };
  unsigned short* abfT = (unsigned short*)alloc(ASZ*2);              // 52.4 MB
  unsigned short* ata  = (unsigned short*)alloc((size_t)NP*1024*1024*2);  // 104.9 MB (tiled)
  float* atb = (float*)alloc(YSZ*4);
  unsigned short* ybf0 = (unsigned short*)alloc(YSZ*2);
  unsigned short* ybf1 = (unsigned short*)alloc(YSZ*2);
  float* w   = (float*)alloc(YSZ*4);
  float* eb  = (float*)alloc(YSZ*4);
  float* h1  = (float*)alloc((size_t)16*3200*4);
  float* h2  = (float*)alloc((size_t)16*6400*4);
  float* h3  = (float*)alloc((size_t)16*12800*4);
  float* adj = (float*)alloc((size_t)16*2500*4);
  float* dm  = (float*)alloc((size_t)16*2500*4);
  float* snb = (float*)alloc((size_t)16*50*4);
  float* hyp = (float*)alloc((size_t)16*80*4);
  float* part= (float*)alloc((size_t)84000000);

  // ---- one-time prep ----
  k_prep<<<dim3(50,8,16), dim3(256), 0, stream>>>(A, abfT);
  k_init<<<dim3(800), dim3(256), 0, stream>>>(y0, ybf0, (int)YSZ);

  // ---- merged: enc-L1 || AtA || Atb || graph (roles interleaved) ----
  k_big<<<dim3(2616), dim3(256), 0, stream>>>(abfT, ata, bin, We1, part, atb,
                                              ei, adj, dm, snb);
  k_enc_reduce<<<dim3(200), dim3(256), 0, stream>>>(part, be1, h1, 3200, 100);

  // ---- encoder L2/L3 ----
  k_enc2<<<dim3(7,100),  dim3(256), 0, stream>>>(h1, We2, part, 3200, 6400, 32, 1);
  k_enc_reduce<<<dim3(400), dim3(256), 0, stream>>>(part, be2, h2, 6400, 100);
  k_enc2<<<dim3(13,100), dim3(256), 0, stream>>>(h2, We3, part, 6400, 12800, 64, 1);
  k_enc_reduce<<<dim3(800), dim3(256), 0, stream>>>(part, be3, h3, 12800, 100);

  // ---- GNN/head + e0 ----
  k_gnn<<<dim3(16), dim3(256), 0, stream>>>(h3, Wc1, bc1, Wc2, bc2, Wf1, bf1, Wf2, bf2, mxp, adj, hyp);
  k_e0<<<dim3(800), dim3(256), 0, stream>>>(u0, dd0, atb, snb, hyp, w, eb);

  // ---- scan: 2 kernels/step (k_dm skipped on last step) ----
  for (int k=0;k<NK;k++){
    const unsigned short* ybin = (k & 1) ? ybf1 : ybf0;
    unsigned short* ybout      = (k & 1) ? ybf0 : ybf1;
    k_z<<<dim3(50,32), dim3(256), 0, stream>>>(ata, ybin, eb, hyp, k, ybout, out);
    if (k < NK-1){
      const unsigned short* ybnew = (k & 1) ? ybf0 : ybf1;
      k_dm<<<dim3(16,16), dim3(256), 0, stream>>>(dm, snb, hyp, k, ybnew, w, eb);
    }
  }
}

// Round 18
// 1316.649 us; speedup vs baseline: 1.0260x; 1.0260x over previous
//
#include <hip/hip_runtime.h>

namespace {
constexpr int NB = 16;    // batch
constexpr int NP = 50;    // P nodes
constexpr int NM = 512;   // M
constexpr int NN = 1024;  // N
constexpr int NK = 20;    // scan steps
constexpr long ASZ = (long)NP * NM * NN;   // 26,214,400
constexpr long YSZ = (long)NB * NP * NN;   // 819,200
}

typedef __attribute__((ext_vector_type(8))) short bf16x8;
typedef __attribute__((ext_vector_type(4))) float f32x4;

__device__ __forceinline__ float lrelu(float x){ return x > 0.f ? x : 0.01f*x; }
__device__ __forceinline__ float bfu(unsigned short x){
  unsigned v = ((unsigned)x) << 16;
  return __builtin_bit_cast(float, v);
}
__device__ __forceinline__ unsigned short f2bf(float f){   // RNE f32->bf16
  unsigned u = __builtin_bit_cast(unsigned, f);
  u += 0x7fffu + ((u >> 16) & 1u);
  return (unsigned short)(u >> 16);
}
// tiled AtA element offset: [ntile=n>>4][ks=k>>5][lr=n&15][kg=(k>>3)&3][e=k&7]
__device__ __forceinline__ long toff(int n, int kk){
  return (long)(n>>4)*16384 + (long)(kk>>5)*512 + (long)((n&15)*32 + ((kk>>3)&3)*8 + (kk&7));
}

// ---------------- A (f32) -> abfT (transposed bf16 [p][n][m]) ----------------
__global__ __launch_bounds__(256) void k_prep(const float* __restrict__ A,
                      unsigned short* __restrict__ abfT){
  const int p = blockIdx.x, mt = blockIdx.y, nt = blockIdx.z;
  const int tid = threadIdx.x;
  __shared__ unsigned short tile[64][72];
  const int m0 = mt*64, n0 = nt*64;
  {
    int r = tid>>2, cs = (tid&3)*16;
    const float* src = A + ((long)p*NM + m0 + r)*NN + n0 + cs;
    unsigned short tmp[16];
    #pragma unroll
    for (int q=0;q<16;q+=4){
      float4 v = *(const float4*)(src+q);
      tmp[q+0]=f2bf(v.x); tmp[q+1]=f2bf(v.y); tmp[q+2]=f2bf(v.z); tmp[q+3]=f2bf(v.w);
    }
    #pragma unroll
    for (int q=0;q<16;q++) tile[r][cs+q] = tmp[q];
  }
  __syncthreads();
  {
    int r = tid>>2, cs = (tid&3)*16;   // r = n-offset, cs = m-offset
    unsigned short* dst = abfT + ((long)p*NN + n0 + r)*NM + m0 + cs;
    unsigned short tmp[16];
    #pragma unroll
    for (int q=0;q<16;q++) tmp[q] = tile[cs+q][r];
    #pragma unroll
    for (int q=0;q<16;q+=8) *(uint4*)(dst+q) = *(const uint4*)&tmp[q];
  }
}

// ---------------- scan-state init: ybf only (bf16 state carrier) ----------------
__global__ void k_init(const float* __restrict__ y0, unsigned short* __restrict__ ybf, int n){
  int e = (blockIdx.x*blockDim.x + threadIdx.x)*4;
  if (e >= n) return;
  float4 a = *(const float4*)(y0+e);
  ushort4 o; o.x=f2bf(a.x); o.y=f2bf(a.y); o.z=f2bf(a.z); o.w=f2bf(a.w);
  *(ushort4*)(ybf+e) = o;
}

// ---------------- w0 = u0*snb - atb ; e0 = w0 + d0*rho_0 ----------------
__global__ __launch_bounds__(256) void k_e0(const float* __restrict__ u0,
      const float* __restrict__ d0, const float* __restrict__ atb,
      const float* __restrict__ snbg, const float* __restrict__ hypg,
      float* __restrict__ w, float* __restrict__ e){
  long i = ((long)blockIdx.x*256 + threadIdx.x)*4;
  if (i >= YSZ) return;
  long bp = i >> 10;          // b*NP+p
  int b = (int)(bp/NP), p = (int)(bp%NP);
  float sp = snbg[b*NP+p], rho = hypg[b*80 + 2];
  float4 uv = *(const float4*)(u0+i);
  float4 dv = *(const float4*)(d0+i);
  float4 av = *(const float4*)(atb+i);
  float4 wv, ev;
  wv.x = uv.x*sp - av.x; wv.y = uv.y*sp - av.y;
  wv.z = uv.z*sp - av.z; wv.w = uv.w*sp - av.w;
  ev.x = wv.x + dv.x*rho; ev.y = wv.y + dv.y*rho;
  ev.z = wv.z + dv.z*rho; ev.w = wv.w + dv.w*rho;
  *(float4*)(w+i) = wv;
  *(float4*)(e+i) = ev;
}

// ================= role bodies (shared by merged kernel) =================

// ---- encoder GEMM body: float4 W stream, acc[16] float4 ----
__device__ __forceinline__ void enc_body(const float* __restrict__ X, const float* __restrict__ W,
                           float* __restrict__ part, int fi, int fo, int ichunk, int actin,
                           int bx, int c, int tid, char* smem){
  float (*xs)[16] = (float(*)[16])smem;   // [64][16]
  const int o0 = (bx*256 + tid)*4;
  const bool ok = o0 < fo;   // fo multiple of 4
  float4 acc[16];
  #pragma unroll
  for (int b=0;b<16;b++){ acc[b].x=0.f; acc[b].y=0.f; acc[b].z=0.f; acc[b].w=0.f; }
  const long ibase = (long)c*ichunk;
  const int xb = tid&15, xio = (tid>>4)*4;
  for (int s=0; s<ichunk; s+=64){
    float4 v = *(const float4*)(X + (long)xb*fi + ibase + s + xio);
    if (actin){ v.x=lrelu(v.x); v.y=lrelu(v.y); v.z=lrelu(v.z); v.w=lrelu(v.w); }
    __syncthreads();
    xs[xio+0][xb]=v.x; xs[xio+1][xb]=v.y; xs[xio+2][xb]=v.z; xs[xio+3][xb]=v.w;
    __syncthreads();
    const float* wp = W + (ibase+s)*fo + o0;
    #pragma unroll 4
    for (int i=0;i<64;i++){
      float4 w;
      if (ok) w = *(const float4*)(wp + (long)i*fo);
      else { w.x=0.f; w.y=0.f; w.z=0.f; w.w=0.f; }
      #pragma unroll
      for (int b2=0;b2<16;b2+=4){
        float4 x4 = *(const float4*)&xs[i][b2];
        acc[b2+0].x += w.x*x4.x; acc[b2+0].y += w.y*x4.x; acc[b2+0].z += w.z*x4.x; acc[b2+0].w += w.w*x4.x;
        acc[b2+1].x += w.x*x4.y; acc[b2+1].y += w.y*x4.y; acc[b2+1].z += w.z*x4.y; acc[b2+1].w += w.w*x4.y;
        acc[b2+2].x += w.x*x4.z; acc[b2+2].y += w.y*x4.z; acc[b2+2].z += w.z*x4.z; acc[b2+2].w += w.w*x4.z;
        acc[b2+3].x += w.x*x4.w; acc[b2+3].y += w.y*x4.w; acc[b2+3].z += w.z*x4.w; acc[b2+3].w += w.w*x4.w;
      }
    }
  }
  if (ok){
    float* pp = part + ((long)c*16)*fo + o0;
    #pragma unroll
    for (int b=0;b<16;b++) *(float4*)(pp + (long)b*fo) = acc[b];
  }
}

// ---- AtA body (tile-pair bi<=bj), bf16 out in TILED layout ----
__device__ __forceinline__ void ata_body(const unsigned short* __restrict__ abfT,
                      unsigned short* __restrict__ ata, int yy_in, int p, int tid, char* smem){
  unsigned short (*pa)[72] = (unsigned short(*)[72])smem;            // [128][72]
  unsigned short (*pb)[72] = (unsigned short(*)[72])(smem + 18432);  // [128][72]
  int yy = yy_in, bi = 0;
  while (yy >= 8 - bi){ yy -= 8 - bi; bi++; }
  const int bj = bi + yy;
  const int i0 = bi*128, j0 = bj*128;
  const int wave = tid>>6, lane = tid&63;
  const int lr = lane&15, kg = lane>>4;
  f32x4 acc[2][8];
  #pragma unroll
  for (int ti=0;ti<2;ti++)
    #pragma unroll
    for (int tj=0;tj<8;tj++) acc[ti][tj] = (f32x4){0.f,0.f,0.f,0.f};
  const unsigned short* Abase = abfT + (long)p*NN*NM;
  for (int mc=0; mc<NM; mc+=64){
    __syncthreads();
    {
      int r = tid>>1, c0 = (tid&1)*32;
      const unsigned short* sa = Abase + (long)(i0 + r)*NM + mc + c0;
      const unsigned short* sb = Abase + (long)(j0 + r)*NM + mc + c0;
      #pragma unroll
      for (int q=0;q<32;q+=8){
        *(uint4*)&pa[r][c0+q] = *(const uint4*)(sa+q);
        *(uint4*)&pb[r][c0+q] = *(const uint4*)(sb+q);
      }
    }
    __syncthreads();
    #pragma unroll
    for (int ks=0; ks<2; ks++){
      bf16x8 av0 = *(const bf16x8*)&pa[wave*32      + lr][ks*32 + kg*8];
      bf16x8 av1 = *(const bf16x8*)&pa[wave*32 + 16 + lr][ks*32 + kg*8];
      #pragma unroll
      for (int tj=0;tj<8;tj++){
        bf16x8 bv = *(const bf16x8*)&pb[tj*16 + lr][ks*32 + kg*8];
        acc[0][tj] = __builtin_amdgcn_mfma_f32_16x16x32_bf16(av0, bv, acc[0][tj], 0,0,0);
        acc[1][tj] = __builtin_amdgcn_mfma_f32_16x16x32_bf16(av1, bv, acc[1][tj], 0,0,0);
      }
    }
  }
  const long pbase = (long)p << 20;
  #pragma unroll
  for (int ti=0; ti<2; ti++){
    const int ib = i0 + wave*32 + ti*16;
    #pragma unroll
    for (int tj=0; tj<8; tj++){
      const int jb = j0 + tj*16;
      unsigned short w[4];
      #pragma unroll
      for (int r=0;r<4;r++) w[r] = f2bf(acc[ti][tj][r]);
      #pragma unroll
      for (int r=0;r<4;r++)
        ata[pbase + toff(ib + kg*4 + r, jb + lr)] = w[r];
      if (bi != bj){
        #pragma unroll
        for (int r=0;r<4;r++)
          ata[pbase + toff(jb + lr, ib + kg*4 + r)] = w[r];
      }
    }
  }
}

// ---- Atb body: atb[b,p,n] = sum_m A[p,m,n]*b[b,p,m] (f32 src) ----
__device__ __forceinline__ void atb_body(const unsigned short* __restrict__ abfT,
                      const float* __restrict__ src, float* __restrict__ z,
                      int p, int gy, int tid, char* smem){
  unsigned short (*tlds)[520] = (unsigned short(*)[520])smem;   // [16][520]
  const int wave = tid>>6, lane = tid&63;
  {
    int b = tid>>4, c0 = (tid&15)*8;
    const float* tr = src + ((long)b*NP + p)*NM;
    #pragma unroll
    for (int it=0; it<4; it++){
      float4 lo = *(const float4*)(tr + it*128 + c0);
      float4 hi = *(const float4*)(tr + it*128 + c0 + 4);
      unsigned short w[8];
      w[0]=f2bf(lo.x); w[1]=f2bf(lo.y); w[2]=f2bf(lo.z); w[3]=f2bf(lo.w);
      w[4]=f2bf(hi.x); w[5]=f2bf(hi.y); w[6]=f2bf(hi.z); w[7]=f2bf(hi.w);
      *(uint4*)&tlds[b][it*128 + c0] = *(const uint4*)w;
    }
  }
  __syncthreads();
  const int lr = lane&15, kg = lane>>4;
  const int nt0 = gy*4 + wave;
  const int n0 = nt0*16, n1 = (nt0+32)*16;
  const unsigned short* b0 = abfT + ((long)p*NN + n0 + lr)*NM + kg*8;
  const unsigned short* b1 = abfT + ((long)p*NN + n1 + lr)*NM + kg*8;
  const unsigned short* tp = &tlds[lr][kg*8];
  f32x4 acc0a={0.f,0.f,0.f,0.f}, acc0b={0.f,0.f,0.f,0.f};
  f32x4 acc1a={0.f,0.f,0.f,0.f}, acc1b={0.f,0.f,0.f,0.f};
  #pragma unroll 4
  for (int ks=0; ks<16; ks+=2){
    bf16x8 t0 = *(const bf16x8*)(tp + ks*32);
    bf16x8 t1 = *(const bf16x8*)(tp + ks*32 + 32);
    bf16x8 b00 = *(const bf16x8*)(b0 + (long)ks*32);
    bf16x8 b01 = *(const bf16x8*)(b0 + (long)ks*32 + 32);
    bf16x8 b10 = *(const bf16x8*)(b1 + (long)ks*32);
    bf16x8 b11 = *(const bf16x8*)(b1 + (long)ks*32 + 32);
    acc0a = __builtin_amdgcn_mfma_f32_16x16x32_bf16(t0, b00, acc0a, 0, 0, 0);
    acc1a = __builtin_amdgcn_mfma_f32_16x16x32_bf16(t0, b10, acc1a, 0, 0, 0);
    acc0b = __builtin_amdgcn_mfma_f32_16x16x32_bf16(t1, b01, acc0b, 0, 0, 0);
    acc1b = __builtin_amdgcn_mfma_f32_16x16x32_bf16(t1, b11, acc1b, 0, 0, 0);
  }
  f32x4 acc0 = acc0a + acc0b;
  f32x4 acc1 = acc1a + acc1b;
  #pragma unroll
  for (int r=0;r<4;r++){
    int bb = kg*4 + r;
    z[((long)bb*NP + p)*NN + n0 + lr] = acc0[r];
    z[((long)bb*NP + p)*NN + n1 + lr] = acc1[r];
  }
}

// ---- graph body (256 threads): adjacency, delta operator, src counts ----
__device__ __forceinline__ void graph_body(const int* __restrict__ ei, float* __restrict__ adjg,
                      float* __restrict__ dmg, float* __restrict__ snbg, int b, int tid, char* smem){
  float* adj = (float*)smem;          // 2500
  float* dm  = adj + 2500;            // 2500
  float* deg = dm + 2500;             // 50
  float* dinv= deg + 50;              // 50
  float* snb = dinv + 50;             // 50
  for (int i=tid;i<2500;i+=256){ adj[i]=0.f; dm[i]=0.f; }
  if (tid<50){ deg[tid]=0.f; snb[tid]=0.f; }
  __syncthreads();
  const int* e = ei + b*800;
  for (int k=tid;k<400;k+=256){
    atomicAdd(&deg[e[400+k]], 1.f);
    atomicAdd(&snb[e[k]], 1.f);
  }
  __syncthreads();
  if (tid<50) dinv[tid] = 1.f / sqrtf(deg[tid] + 1.f);
  __syncthreads();
  for (int k=tid;k<400;k+=256){
    int s = e[k], d = e[400+k];
    atomicAdd(&adj[d*50+s], dinv[s]*dinv[d]);
    atomicAdd(&dm[s*50+s],  1.f); atomicAdd(&dm[s*50+d], -1.f);
    atomicAdd(&dm[d*50+d],  1.f); atomicAdd(&dm[d*50+s], -1.f);
  }
  __syncthreads();
  if (tid<50) adj[tid*50+tid] += dinv[tid]*dinv[tid];
  __syncthreads();
  for (int i=tid;i<2500;i+=256){ adjg[b*2500+i]=adj[i]; dmg[b*2500+i]=dm[i]; }
  if (tid<50) snbg[b*50+tid]=snb[tid];
}

// ---------------- merged (contiguous roles): enc-L1 (400) ∥ AtA (1800) ∥ Atb (400) ∥ graph (16) ----------------
__global__ __launch_bounds__(256) void k_big(const unsigned short* __restrict__ abfT,
      unsigned short* __restrict__ ata, const float* __restrict__ bin,
      const float* __restrict__ We1, float* __restrict__ part,
      float* __restrict__ atb, const int* __restrict__ ei,
      float* __restrict__ adjg, float* __restrict__ dmg, float* __restrict__ snbg){
  __shared__ __align__(16) char smem[36864];
  const int bid = blockIdx.x, tid = threadIdx.x;
  if (bid < 400){
    enc_body(bin, We1, part, 25600, 3200, 256, 0, bid & 3, bid >> 2, tid, smem);
  } else if (bid < 2200){
    int a = bid - 400;
    ata_body(abfT, ata, a % 36, a / 36, tid, smem);
  } else if (bid < 2600){
    int a = bid - 2200;
    atb_body(abfT, bin, atb, a >> 3, a & 7, tid, smem);
  } else {
    graph_body(ei, adjg, dmg, snbg, bid - 2600, tid, smem);
  }
}

// ---------------- standalone encoder GEMM (L2/L3) ----------------
__global__ __launch_bounds__(256) void k_enc2(const float* __restrict__ X, const float* __restrict__ W,
                           float* __restrict__ part, int fi, int fo, int ichunk, int actin){
  __shared__ __align__(16) char smem[4096];
  enc_body(X, W, part, fi, fo, ichunk, actin, blockIdx.x, blockIdx.y, threadIdx.x, smem);
}

__global__ void k_enc_reduce(const float* __restrict__ part, const float* __restrict__ bias,
                             float* __restrict__ out, int fo, int nchunk){
  int i = blockIdx.x*256 + threadIdx.x;
  if (i >= 16*fo) return;
  int o = i % fo;
  float s = bias[o];
  for (int c=0;c<nchunk;c++) s += part[(long)c*16*fo + i];
  out[i] = s;
}

// ---------------- fused GCN x2 + head ----------------
__global__ __launch_bounds__(256) void k_gnn(const float* __restrict__ h3,
     const float* __restrict__ Wc1, const float* __restrict__ bc1,
     const float* __restrict__ Wc2, const float* __restrict__ bc2,
     const float* __restrict__ Wf1, const float* __restrict__ bf1,
     const float* __restrict__ Wf2, const float* __restrict__ bf2,
     const float* __restrict__ maxp, const float* __restrict__ adjg,
     float* __restrict__ hypg){
  const int b = blockIdx.x, tid = threadIdx.x;
  __shared__ float adj[2500];
  __shared__ float bufA[6400];
  __shared__ float bufB[6400];
  __shared__ float xm[128], hv1[64], raw[80];
  for (int i=tid;i<2500;i+=256) adj[i] = adjg[b*2500+i];

  const int j = tid & 127, nh = tid >> 7;
  float acc[25];
  #pragma unroll
  for (int q=0;q<25;q++) acc[q]=0.f;
  for (int ic=0; ic<4; ic++){
    __syncthreads();
    for (int e=tid; e<800; e+=256){
      int n = e>>4, seg = (e&15)*4;
      *(float4*)&bufB[n*64+seg] = *(const float4*)(h3 + (long)b*12800 + n*256 + ic*64 + seg);
    }
    __syncthreads();
    for (int i=0;i<64;i+=4){
      float w0 = Wc1[(long)(ic*64+i+0)*128 + j];
      float w1 = Wc1[(long)(ic*64+i+1)*128 + j];
      float w2 = Wc1[(long)(ic*64+i+2)*128 + j];
      float w3 = Wc1[(long)(ic*64+i+3)*128 + j];
      #pragma unroll
      for (int q=0;q<25;q++){
        float4 xv = *(const float4*)&bufB[(nh*25+q)*64 + i];
        acc[q] += xv.x*w0 + xv.y*w1 + xv.z*w2 + xv.w*w3;
      }
    }
  }
  __syncthreads();
  #pragma unroll
  for (int q=0;q<25;q++) bufA[(nh*25+q)*128 + j] = acc[q];
  __syncthreads();
  {
    float a2[25];
    float bv = bc1[j];
    #pragma unroll
    for (int q=0;q<25;q++) a2[q]=bv;
    for (int qq=0; qq<50; qq++){
      float hvv = bufA[qq*128 + j];
      #pragma unroll
      for (int q=0;q<25;q++) a2[q] += adj[(nh*25+q)*50 + qq]*hvv;
    }
    __syncthreads();
    #pragma unroll
    for (int q=0;q<25;q++) bufB[(nh*25+q)*128 + j] = lrelu(a2[q]);
  }
  __syncthreads();
  {
    float a2[25];
    #pragma unroll
    for (int q=0;q<25;q++) a2[q]=0.f;
    for (int i=0;i<128;i+=4){
      float w0 = Wc2[(long)(i+0)*128 + j];
      float w1 = Wc2[(long)(i+1)*128 + j];
      float w2 = Wc2[(long)(i+2)*128 + j];
      float w3 = Wc2[(long)(i+3)*128 + j];
      #pragma unroll
      for (int q=0;q<25;q++){
        float4 xv = *(const float4*)&bufB[(nh*25+q)*128 + i];
        a2[q] += xv.x*w0 + xv.y*w1 + xv.z*w2 + xv.w*w3;
      }
    }
    __syncthreads();
    #pragma unroll
    for (int q=0;q<25;q++) bufA[(nh*25+q)*128 + j] = a2[q];
  }
  __syncthreads();
  {
    float a2[25];
    float bv = bc2[j];
    #pragma unroll
    for (int q=0;q<25;q++) a2[q]=bv;
    for (int qq=0; qq<50; qq++){
      float hvv = bufA[qq*128 + j];
      #pragma unroll
      for (int q=0;q<25;q++) a2[q] += adj[(nh*25+q)*50 + qq]*hvv;
    }
    __syncthreads();
    #pragma unroll
    for (int q=0;q<25;q++) bufB[(nh*25+q)*128 + j] = lrelu(a2[q]);
  }
  __syncthreads();
  if (tid < 128){
    float s = 0.f;
    for (int n=0;n<50;n++) s += bufB[n*128 + tid];
    xm[tid] = s * (1.f/50.f);
  }
  __syncthreads();
  if (tid < 64){
    float s = bf1[tid];
    for (int i=0;i<128;i++) s += xm[i]*Wf1[i*64 + tid];
    hv1[tid] = lrelu(s);
  }
  __syncthreads();
  if (tid < 80){
    float s = bf2[tid];
    for (int i=0;i<64;i++) s += hv1[i]*Wf2[i*80 + tid];
    raw[tid] = s;
  }
  __syncthreads();
  if (tid < 4){
    float c = 0.f;
    for (int k=0;k<20;k++){
      c += raw[k*4 + tid];
      hypg[b*80 + k*4 + tid] = maxp[tid] / (1.f + expf(-c));
    }
  }
}

// ---------------- scan: split-K z = AtA[p] @ y + fused y-update (bf16 state carrier) ----------------
__global__ __launch_bounds__(256, 6) void k_z(const unsigned short* __restrict__ ata,
      const unsigned short* __restrict__ ybin, const float* __restrict__ ebuf,
      const float* __restrict__ hypg, int k,
      unsigned short* __restrict__ ybout, float* __restrict__ yout){
  const int p = blockIdx.x;
  const int tid = threadIdx.x, wave = tid>>6, lane = tid&63;
  const int lr = lane&15, kg = lane>>4;
  const int tl = wave>>1;                        // tile local 0..1
  const int kh = wave&1;                         // K-half
  const int t  = blockIdx.y*2 + tl;              // n-tile 0..63
  const int n0 = t*16;
  __shared__ float part[2][16][17];
  const unsigned short* bp  = ata + ((long)p<<20) + (long)t*16384 + kh*8192 + lr*32 + kg*8;
  const unsigned short* ypg = ybin + ((long)lr*NP + p)*NN + kh*512 + kg*8;

  // epilogue operand preload (low-half waves only; overlaps MFMA)
  float yv4[4], e4[4];
  float4 hp4[4];
  if (kh == 0){
    #pragma unroll
    for (int r=0;r<4;r++){
      const int b = kg*4 + r;
      const long idx = ((long)b*NP + p)*NN + n0 + lr;
      yv4[r] = bfu(ybin[idx]); e4[r] = ebuf[idx];
      hp4[r] = *(const float4*)(hypg + b*80 + k*4);
    }
  }

  f32x4 a0={0.f,0.f,0.f,0.f}, a1={0.f,0.f,0.f,0.f}, a2={0.f,0.f,0.f,0.f}, a3={0.f,0.f,0.f,0.f};
  #pragma unroll
  for (int i=0;i<4;i++){
    bf16x8 b0 = *(const bf16x8*)(bp + (i*4+0)*512);
    bf16x8 b1 = *(const bf16x8*)(bp + (i*4+1)*512);
    bf16x8 b2 = *(const bf16x8*)(bp + (i*4+2)*512);
    bf16x8 b3 = *(const bf16x8*)(bp + (i*4+3)*512);
    bf16x8 q0 = *(const bf16x8*)(ypg + (i*4+0)*32);
    bf16x8 q1 = *(const bf16x8*)(ypg + (i*4+1)*32);
    bf16x8 q2 = *(const bf16x8*)(ypg + (i*4+2)*32);
    bf16x8 q3 = *(const bf16x8*)(ypg + (i*4+3)*32);
    a0 = __builtin_amdgcn_mfma_f32_16x16x32_bf16(q0, b0, a0, 0,0,0);
    a1 = __builtin_amdgcn_mfma_f32_16x16x32_bf16(q1, b1, a1, 0,0,0);
    a2 = __builtin_amdgcn_mfma_f32_16x16x32_bf16(q2, b2, a2, 0,0,0);
    a3 = __builtin_amdgcn_mfma_f32_16x16x32_bf16(q3, b3, a3, 0,0,0);
  }
  f32x4 zh = (a0 + a1) + (a2 + a3);
  if (kh == 1){
    #pragma unroll
    for (int r=0;r<4;r++) part[tl][kg*4+r][lr] = zh[r];
  }
  __syncthreads();
  if (kh == 0){
    #pragma unroll
    for (int r=0;r<4;r++){
      const int b = kg*4 + r;
      const long idx = ((long)b*NP + p)*NN + n0 + lr;
      float z = zh[r] + part[tl][kg*4+r][lr];
      float yv = yv4[r];
      float g = z + ((yv>0.f)?1.f:((yv<0.f)?-1.f:0.f))*hp4[r].y + e4[r];
      float ynv = yv - hp4[r].x*g;
      ybout[idx] = f2bf(ynv); yout[(long)k*YSZ + idx] = ynv;
    }
  }
}

// ---------------- scan: dl = Dm @ y_{k+1} (bf16) ; w += dl*eta*snb ; e = w + dl*rho_{k+1} ----------------
__global__ __launch_bounds__(256) void k_dm(const float* __restrict__ dmg,
      const float* __restrict__ snbg, const float* __restrict__ hypg, int k,
      const unsigned short* __restrict__ ybf, float* __restrict__ w, float* __restrict__ e){
  const int b = blockIdx.x, n0 = blockIdx.y*64, tid = threadIdx.x;
  __shared__ float ys[50][64];
  __shared__ float dms[2500];
  for (int i=tid;i<2500;i+=256) dms[i] = dmg[b*2500+i];
  for (int i=tid; i<3200; i+=256){
    int p=i>>6, nn=i&63;
    ys[p][nn] = bfu(ybf[((long)b*NP+p)*NN + n0 + nn]);
  }
  __syncthreads();
  const float eta = hypg[b*80 + k*4 + 3];
  const float rhon = hypg[b*80 + (k+1)*4 + 2];
  for (int i=tid; i<3200; i+=256){
    int p=i>>6, nn=i&63;
    float s=0.f;
    #pragma unroll 10
    for (int q=0;q<NP;q++) s += dms[p*50+q]*ys[q][nn];
    long idx = ((long)b*NP+p)*NN + n0 + nn;
    float wn = w[idx] + s*eta*snbg[b*NP+p];
    w[idx] = wn;
    e[idx] = wn + s*rhon;
  }
}

extern "C" void kernel_launch(void* const* d_in, const int* in_sizes, int n_in,
                              void* d_out, int out_size, void* d_ws, size_t ws_size,
                              hipStream_t stream){
  (void)in_sizes; (void)n_in; (void)out_size; (void)ws_size;
  const float* bin = (const float*)d_in[0];
  const float* A   = (const float*)d_in[1];
  const int*   ei  = (const int*)d_in[2];
  const float* mxp = (const float*)d_in[3];
  const float* We1 = (const float*)d_in[4];  const float* be1 = (const float*)d_in[5];
  const float* We2 = (const float*)d_in[6];  const float* be2 = (const float*)d_in[7];
  const float* We3 = (const float*)d_in[8];  const float* be3 = (const float*)d_in[9];
  const float* Wc1 = (const float*)d_in[10]; const float* bc1 = (const float*)d_in[11];
  const float* Wc2 = (const float*)d_in[12]; const float* bc2 = (const float*)d_in[13];
  const float* Wf1 = (const float*)d_in[14]; const float* bf1 = (const float*)d_in[15];
  const float* Wf2 = (const float*)d_in[16]; const float* bf2 = (const float*)d_in[17];
  const float* y0  = (const float*)d_in[18];
  const float* u0  = (const float*)d_in[19];
  const float* dd0 = (const float*)d_in[20];
  float* out = (float*)d_out;

  char* cur = (char*)d_ws;
  auto alloc = [&](size_t bytes)->void*{
    void* pp = (void*)cur; cur += (bytes + 255) & ~(size_t)255; return pp;
  };
  unsigned short* abfT = (unsigned short*)alloc(ASZ*2);              // 52.4 MB
  unsigned short* ata  = (unsigned short*)alloc((size_t)NP*1024*1024*2);  // 104.9 MB (tiled)
  float* atb = (float*)alloc(YSZ*4);
  unsigned short* ybf0 = (unsigned short*)alloc(YSZ*2);
  unsigned short* ybf1 = (unsigned short*)alloc(YSZ*2);
  float* w   = (float*)alloc(YSZ*4);
  float* eb  = (float*)alloc(YSZ*4);
  float* h1  = (float*)alloc((size_t)16*3200*4);
  float* h2  = (float*)alloc((size_t)16*6400*4);
  float* h3  = (float*)alloc((size_t)16*12800*4);
  float* adj = (float*)alloc((size_t)16*2500*4);
  float* dm  = (float*)alloc((size_t)16*2500*4);
  float* snb = (float*)alloc((size_t)16*50*4);
  float* hyp = (float*)alloc((size_t)16*80*4);
  float* part= (float*)alloc((size_t)84000000);

  // ---- one-time prep ----
  k_prep<<<dim3(50,8,16), dim3(256), 0, stream>>>(A, abfT);
  k_init<<<dim3(800), dim3(256), 0, stream>>>(y0, ybf0, (int)YSZ);

  // ---- merged: enc-L1 || AtA || Atb || graph (contiguous roles) ----
  k_big<<<dim3(2616), dim3(256), 0, stream>>>(abfT, ata, bin, We1, part, atb,
                                              ei, adj, dm, snb);
  k_enc_reduce<<<dim3(200), dim3(256), 0, stream>>>(part, be1, h1, 3200, 100);

  // ---- encoder L2/L3 ----
  k_enc2<<<dim3(7,100),  dim3(256), 0, stream>>>(h1, We2, part, 3200, 6400, 32, 1);
  k_enc_reduce<<<dim3(400), dim3(256), 0, stream>>>(part, be2, h2, 6400, 100);
  k_enc2<<<dim3(13,100), dim3(256), 0, stream>>>(h2, We3, part, 6400, 12800, 64, 1);
  k_enc_reduce<<<dim3(800), dim3(256), 0, stream>>>(part, be3, h3, 12800, 100);

  // ---- GNN/head + e0 ----
  k_gnn<<<dim3(16), dim3(256), 0, stream>>>(h3, Wc1, bc1, Wc2, bc2, Wf1, bf1, Wf2, bf2, mxp, adj, hyp);
  k_e0<<<dim3(800), dim3(256), 0, stream>>>(u0, dd0, atb, snb, hyp, w, eb);

  // ---- scan: 2 kernels/step (k_dm skipped on last step) ----
  for (int k=0;k<NK;k++){
    const unsigned short* ybin = (k & 1) ? ybf1 : ybf0;
    unsigned short* ybout      = (k & 1) ? ybf0 : ybf1;
    k_z<<<dim3(50,32), dim3(256), 0, stream>>>(ata, ybin, eb, hyp, k, ybout, out);
    if (k < NK-1){
      const unsigned short* ybnew = (k & 1) ? ybf0 : ybf1;
      k_dm<<<dim3(16,16), dim3(256), 0, stream>>>(dm, snb, hyp, k, ybnew, w, eb);
    }
  }
}

// Round 19
// 1301.033 us; speedup vs baseline: 1.0383x; 1.0120x over previous
//
#include <hip/hip_runtime.h>

namespace {
constexpr int NB = 16;    // batch
constexpr int NP = 50;    // P nodes
constexpr int NM = 512;   // M
constexpr int NN = 1024;  // N
constexpr int NK = 20;    // scan steps
constexpr long ASZ = (long)NP * NM * NN;   // 26,214,400
constexpr long YSZ = (long)NB * NP * NN;   // 819,200
}

typedef __attribute__((ext_vector_type(8))) short bf16x8;
typedef __attribute__((ext_vector_type(4))) float f32x4;

__device__ __forceinline__ float lrelu(float x){ return x > 0.f ? x : 0.01f*x; }
__device__ __forceinline__ float bfu(unsigned short x){
  unsigned v = ((unsigned)x) << 16;
  return __builtin_bit_cast(float, v);
}
__device__ __forceinline__ unsigned short f2bf(float f){   // RNE f32->bf16
  unsigned u = __builtin_bit_cast(unsigned, f);
  u += 0x7fffu + ((u >> 16) & 1u);
  return (unsigned short)(u >> 16);
}
// tiled AtA element offset: [ntile=n>>4][ks=k>>5][lr=n&15][kg=(k>>3)&3][e=k&7]
__device__ __forceinline__ long toff(int n, int kk){
  return (long)(n>>4)*16384 + (long)(kk>>5)*512 + (long)((n&15)*32 + ((kk>>3)&3)*8 + (kk&7));
}

// ---------------- A (f32) -> abfT (transposed bf16 [p][n][m]) ----------------
__global__ __launch_bounds__(256) void k_prep(const float* __restrict__ A,
                      unsigned short* __restrict__ abfT){
  const int p = blockIdx.x, mt = blockIdx.y, nt = blockIdx.z;
  const int tid = threadIdx.x;
  __shared__ unsigned short tile[64][72];
  const int m0 = mt*64, n0 = nt*64;
  {
    int r = tid>>2, cs = (tid&3)*16;
    const float* src = A + ((long)p*NM + m0 + r)*NN + n0 + cs;
    unsigned short tmp[16];
    #pragma unroll
    for (int q=0;q<16;q+=4){
      float4 v = *(const float4*)(src+q);
      tmp[q+0]=f2bf(v.x); tmp[q+1]=f2bf(v.y); tmp[q+2]=f2bf(v.z); tmp[q+3]=f2bf(v.w);
    }
    #pragma unroll
    for (int q=0;q<16;q++) tile[r][cs+q] = tmp[q];
  }
  __syncthreads();
  {
    int r = tid>>2, cs = (tid&3)*16;   // r = n-offset, cs = m-offset
    unsigned short* dst = abfT + ((long)p*NN + n0 + r)*NM + m0 + cs;
    unsigned short tmp[16];
    #pragma unroll
    for (int q=0;q<16;q++) tmp[q] = tile[cs+q][r];
    #pragma unroll
    for (int q=0;q<16;q+=8) *(uint4*)(dst+q) = *(const uint4*)&tmp[q];
  }
}

// ---------------- scan-state init: ybf only (bf16 state carrier) ----------------
__global__ void k_init(const float* __restrict__ y0, unsigned short* __restrict__ ybf, int n){
  int e = (blockIdx.x*blockDim.x + threadIdx.x)*4;
  if (e >= n) return;
  float4 a = *(const float4*)(y0+e);
  ushort4 o; o.x=f2bf(a.x); o.y=f2bf(a.y); o.z=f2bf(a.z); o.w=f2bf(a.w);
  *(ushort4*)(ybf+e) = o;
}

// ---------------- w0 = u0*snb - atb ; e0 = w0 + d0*rho_0 ----------------
__global__ __launch_bounds__(256) void k_e0(const float* __restrict__ u0,
      const float* __restrict__ d0, const float* __restrict__ atb,
      const float* __restrict__ snbg, const float* __restrict__ hypg,
      float* __restrict__ w, float* __restrict__ e){
  long i = ((long)blockIdx.x*256 + threadIdx.x)*4;
  if (i >= YSZ) return;
  long bp = i >> 10;          // b*NP+p
  int b = (int)(bp/NP), p = (int)(bp%NP);
  float sp = snbg[b*NP+p], rho = hypg[b*80 + 2];
  float4 uv = *(const float4*)(u0+i);
  float4 dv = *(const float4*)(d0+i);
  float4 av = *(const float4*)(atb+i);
  float4 wv, ev;
  wv.x = uv.x*sp - av.x; wv.y = uv.y*sp - av.y;
  wv.z = uv.z*sp - av.z; wv.w = uv.w*sp - av.w;
  ev.x = wv.x + dv.x*rho; ev.y = wv.y + dv.y*rho;
  ev.z = wv.z + dv.z*rho; ev.w = wv.w + dv.w*rho;
  *(float4*)(w+i) = wv;
  *(float4*)(e+i) = ev;
}

// ================= role bodies (shared by merged kernel) =================

// ---- encoder GEMM body: float4 W stream, acc[16] float4 ----
__device__ __forceinline__ void enc_body(const float* __restrict__ X, const float* __restrict__ W,
                           float* __restrict__ part, int fi, int fo, int ichunk, int actin,
                           int bx, int c, int tid, char* smem){
  float (*xs)[16] = (float(*)[16])smem;   // [64][16]
  const int o0 = (bx*256 + tid)*4;
  const bool ok = o0 < fo;   // fo multiple of 4
  float4 acc[16];
  #pragma unroll
  for (int b=0;b<16;b++){ acc[b].x=0.f; acc[b].y=0.f; acc[b].z=0.f; acc[b].w=0.f; }
  const long ibase = (long)c*ichunk;
  const int xb = tid&15, xio = (tid>>4)*4;
  for (int s=0; s<ichunk; s+=64){
    float4 v = *(const float4*)(X + (long)xb*fi + ibase + s + xio);
    if (actin){ v.x=lrelu(v.x); v.y=lrelu(v.y); v.z=lrelu(v.z); v.w=lrelu(v.w); }
    __syncthreads();
    xs[xio+0][xb]=v.x; xs[xio+1][xb]=v.y; xs[xio+2][xb]=v.z; xs[xio+3][xb]=v.w;
    __syncthreads();
    const float* wp = W + (ibase+s)*fo + o0;
    #pragma unroll 4
    for (int i=0;i<64;i++){
      float4 w;
      if (ok) w = *(const float4*)(wp + (long)i*fo);
      else { w.x=0.f; w.y=0.f; w.z=0.f; w.w=0.f; }
      #pragma unroll
      for (int b2=0;b2<16;b2+=4){
        float4 x4 = *(const float4*)&xs[i][b2];
        acc[b2+0].x += w.x*x4.x; acc[b2+0].y += w.y*x4.x; acc[b2+0].z += w.z*x4.x; acc[b2+0].w += w.w*x4.x;
        acc[b2+1].x += w.x*x4.y; acc[b2+1].y += w.y*x4.y; acc[b2+1].z += w.z*x4.y; acc[b2+1].w += w.w*x4.y;
        acc[b2+2].x += w.x*x4.z; acc[b2+2].y += w.y*x4.z; acc[b2+2].z += w.z*x4.z; acc[b2+2].w += w.w*x4.z;
        acc[b2+3].x += w.x*x4.w; acc[b2+3].y += w.y*x4.w; acc[b2+3].z += w.z*x4.w; acc[b2+3].w += w.w*x4.w;
      }
    }
  }
  if (ok){
    float* pp = part + ((long)c*16)*fo + o0;
    #pragma unroll
    for (int b=0;b<16;b++) *(float4*)(pp + (long)b*fo) = acc[b];
  }
}

// ---- AtA body (tile-pair bi<=bj), bf16 out in TILED layout ----
__device__ __forceinline__ void ata_body(const unsigned short* __restrict__ abfT,
                      unsigned short* __restrict__ ata, int yy_in, int p, int tid, char* smem){
  unsigned short (*pa)[72] = (unsigned short(*)[72])smem;            // [128][72]
  unsigned short (*pb)[72] = (unsigned short(*)[72])(smem + 18432);  // [128][72]
  int yy = yy_in, bi = 0;
  while (yy >= 8 - bi){ yy -= 8 - bi; bi++; }
  const int bj = bi + yy;
  const int i0 = bi*128, j0 = bj*128;
  const int wave = tid>>6, lane = tid&63;
  const int lr = lane&15, kg = lane>>4;
  f32x4 acc[2][8];
  #pragma unroll
  for (int ti=0;ti<2;ti++)
    #pragma unroll
    for (int tj=0;tj<8;tj++) acc[ti][tj] = (f32x4){0.f,0.f,0.f,0.f};
  const unsigned short* Abase = abfT + (long)p*NN*NM;
  for (int mc=0; mc<NM; mc+=64){
    __syncthreads();
    {
      int r = tid>>1, c0 = (tid&1)*32;
      const unsigned short* sa = Abase + (long)(i0 + r)*NM + mc + c0;
      const unsigned short* sb = Abase + (long)(j0 + r)*NM + mc + c0;
      #pragma unroll
      for (int q=0;q<32;q+=8){
        *(uint4*)&pa[r][c0+q] = *(const uint4*)(sa+q);
        *(uint4*)&pb[r][c0+q] = *(const uint4*)(sb+q);
      }
    }
    __syncthreads();
    #pragma unroll
    for (int ks=0; ks<2; ks++){
      bf16x8 av0 = *(const bf16x8*)&pa[wave*32      + lr][ks*32 + kg*8];
      bf16x8 av1 = *(const bf16x8*)&pa[wave*32 + 16 + lr][ks*32 + kg*8];
      #pragma unroll
      for (int tj=0;tj<8;tj++){
        bf16x8 bv = *(const bf16x8*)&pb[tj*16 + lr][ks*32 + kg*8];
        acc[0][tj] = __builtin_amdgcn_mfma_f32_16x16x32_bf16(av0, bv, acc[0][tj], 0,0,0);
        acc[1][tj] = __builtin_amdgcn_mfma_f32_16x16x32_bf16(av1, bv, acc[1][tj], 0,0,0);
      }
    }
  }
  const long pbase = (long)p << 20;
  #pragma unroll
  for (int ti=0; ti<2; ti++){
    const int ib = i0 + wave*32 + ti*16;
    #pragma unroll
    for (int tj=0; tj<8; tj++){
      const int jb = j0 + tj*16;
      unsigned short w[4];
      #pragma unroll
      for (int r=0;r<4;r++) w[r] = f2bf(acc[ti][tj][r]);
      #pragma unroll
      for (int r=0;r<4;r++)
        ata[pbase + toff(ib + kg*4 + r, jb + lr)] = w[r];
      if (bi != bj){
        #pragma unroll
        for (int r=0;r<4;r++)
          ata[pbase + toff(jb + lr, ib + kg*4 + r)] = w[r];
      }
    }
  }
}

// ---- Atb body: atb[b,p,n] = sum_m A[p,m,n]*b[b,p,m] (f32 src) ----
__device__ __forceinline__ void atb_body(const unsigned short* __restrict__ abfT,
                      const float* __restrict__ src, float* __restrict__ z,
                      int p, int gy, int tid, char* smem){
  unsigned short (*tlds)[520] = (unsigned short(*)[520])smem;   // [16][520]
  const int wave = tid>>6, lane = tid&63;
  {
    int b = tid>>4, c0 = (tid&15)*8;
    const float* tr = src + ((long)b*NP + p)*NM;
    #pragma unroll
    for (int it=0; it<4; it++){
      float4 lo = *(const float4*)(tr + it*128 + c0);
      float4 hi = *(const float4*)(tr + it*128 + c0 + 4);
      unsigned short w[8];
      w[0]=f2bf(lo.x); w[1]=f2bf(lo.y); w[2]=f2bf(lo.z); w[3]=f2bf(lo.w);
      w[4]=f2bf(hi.x); w[5]=f2bf(hi.y); w[6]=f2bf(hi.z); w[7]=f2bf(hi.w);
      *(uint4*)&tlds[b][it*128 + c0] = *(const uint4*)w;
    }
  }
  __syncthreads();
  const int lr = lane&15, kg = lane>>4;
  const int nt0 = gy*4 + wave;
  const int n0 = nt0*16, n1 = (nt0+32)*16;
  const unsigned short* b0 = abfT + ((long)p*NN + n0 + lr)*NM + kg*8;
  const unsigned short* b1 = abfT + ((long)p*NN + n1 + lr)*NM + kg*8;
  const unsigned short* tp = &tlds[lr][kg*8];
  f32x4 acc0a={0.f,0.f,0.f,0.f}, acc0b={0.f,0.f,0.f,0.f};
  f32x4 acc1a={0.f,0.f,0.f,0.f}, acc1b={0.f,0.f,0.f,0.f};
  #pragma unroll 4
  for (int ks=0; ks<16; ks+=2){
    bf16x8 t0 = *(const bf16x8*)(tp + ks*32);
    bf16x8 t1 = *(const bf16x8*)(tp + ks*32 + 32);
    bf16x8 b00 = *(const bf16x8*)(b0 + (long)ks*32);
    bf16x8 b01 = *(const bf16x8*)(b0 + (long)ks*32 + 32);
    bf16x8 b10 = *(const bf16x8*)(b1 + (long)ks*32);
    bf16x8 b11 = *(const bf16x8*)(b1 + (long)ks*32 + 32);
    acc0a = __builtin_amdgcn_mfma_f32_16x16x32_bf16(t0, b00, acc0a, 0, 0, 0);
    acc1a = __builtin_amdgcn_mfma_f32_16x16x32_bf16(t0, b10, acc1a, 0, 0, 0);
    acc0b = __builtin_amdgcn_mfma_f32_16x16x32_bf16(t1, b01, acc0b, 0, 0, 0);
    acc1b = __builtin_amdgcn_mfma_f32_16x16x32_bf16(t1, b11, acc1b, 0, 0, 0);
  }
  f32x4 acc0 = acc0a + acc0b;
  f32x4 acc1 = acc1a + acc1b;
  #pragma unroll
  for (int r=0;r<4;r++){
    int bb = kg*4 + r;
    z[((long)bb*NP + p)*NN + n0 + lr] = acc0[r];
    z[((long)bb*NP + p)*NN + n1 + lr] = acc1[r];
  }
}

// ---- graph body (256 threads): adjacency, delta operator, src counts ----
__device__ __forceinline__ void graph_body(const int* __restrict__ ei, float* __restrict__ adjg,
                      float* __restrict__ dmg, float* __restrict__ snbg, int b, int tid, char* smem){
  float* adj = (float*)smem;          // 2500
  float* dm  = adj + 2500;            // 2500
  float* deg = dm + 2500;             // 50
  float* dinv= deg + 50;              // 50
  float* snb = dinv + 50;             // 50
  for (int i=tid;i<2500;i+=256){ adj[i]=0.f; dm[i]=0.f; }
  if (tid<50){ deg[tid]=0.f; snb[tid]=0.f; }
  __syncthreads();
  const int* e = ei + b*800;
  for (int k=tid;k<400;k+=256){
    atomicAdd(&deg[e[400+k]], 1.f);
    atomicAdd(&snb[e[k]], 1.f);
  }
  __syncthreads();
  if (tid<50) dinv[tid] = 1.f / sqrtf(deg[tid] + 1.f);
  __syncthreads();
  for (int k=tid;k<400;k+=256){
    int s = e[k], d = e[400+k];
    atomicAdd(&adj[d*50+s], dinv[s]*dinv[d]);
    atomicAdd(&dm[s*50+s],  1.f); atomicAdd(&dm[s*50+d], -1.f);
    atomicAdd(&dm[d*50+d],  1.f); atomicAdd(&dm[d*50+s], -1.f);
  }
  __syncthreads();
  if (tid<50) adj[tid*50+tid] += dinv[tid]*dinv[tid];
  __syncthreads();
  for (int i=tid;i<2500;i+=256){ adjg[b*2500+i]=adj[i]; dmg[b*2500+i]=dm[i]; }
  if (tid<50) snbg[b*50+tid]=snb[tid];
}

// ---------------- merged (contiguous roles): enc-L1 (400) ∥ AtA (1800) ∥ Atb (400) ∥ graph (16) ----------------
__global__ __launch_bounds__(256) void k_big(const unsigned short* __restrict__ abfT,
      unsigned short* __restrict__ ata, const float* __restrict__ bin,
      const float* __restrict__ We1, float* __restrict__ part,
      float* __restrict__ atb, const int* __restrict__ ei,
      float* __restrict__ adjg, float* __restrict__ dmg, float* __restrict__ snbg){
  __shared__ __align__(16) char smem[36864];
  const int bid = blockIdx.x, tid = threadIdx.x;
  if (bid < 400){
    enc_body(bin, We1, part, 25600, 3200, 256, 0, bid & 3, bid >> 2, tid, smem);
  } else if (bid < 2200){
    int a = bid - 400;
    ata_body(abfT, ata, a % 36, a / 36, tid, smem);
  } else if (bid < 2600){
    int a = bid - 2200;
    atb_body(abfT, bin, atb, a >> 3, a & 7, tid, smem);
  } else {
    graph_body(ei, adjg, dmg, snbg, bid - 2600, tid, smem);
  }
}

// ---------------- standalone encoder GEMM (L2/L3) ----------------
__global__ __launch_bounds__(256) void k_enc2(const float* __restrict__ X, const float* __restrict__ W,
                           float* __restrict__ part, int fi, int fo, int ichunk, int actin){
  __shared__ __align__(16) char smem[4096];
  enc_body(X, W, part, fi, fo, ichunk, actin, blockIdx.x, blockIdx.y, threadIdx.x, smem);
}

__global__ void k_enc_reduce(const float* __restrict__ part, const float* __restrict__ bias,
                             float* __restrict__ out, int fo, int nchunk){
  int i = blockIdx.x*256 + threadIdx.x;
  if (i >= 16*fo) return;
  int o = i % fo;
  float s = bias[o];
  for (int c=0;c<nchunk;c++) s += part[(long)c*16*fo + i];
  out[i] = s;
}

// ---------------- fused GCN x2 + head ----------------
__global__ __launch_bounds__(256) void k_gnn(const float* __restrict__ h3,
     const float* __restrict__ Wc1, const float* __restrict__ bc1,
     const float* __restrict__ Wc2, const float* __restrict__ bc2,
     const float* __restrict__ Wf1, const float* __restrict__ bf1,
     const float* __restrict__ Wf2, const float* __restrict__ bf2,
     const float* __restrict__ maxp, const float* __restrict__ adjg,
     float* __restrict__ hypg){
  const int b = blockIdx.x, tid = threadIdx.x;
  __shared__ float adj[2500];
  __shared__ float bufA[6400];
  __shared__ float bufB[6400];
  __shared__ float xm[128], hv1[64], raw[80];
  for (int i=tid;i<2500;i+=256) adj[i] = adjg[b*2500+i];

  const int j = tid & 127, nh = tid >> 7;
  float acc[25];
  #pragma unroll
  for (int q=0;q<25;q++) acc[q]=0.f;
  for (int ic=0; ic<4; ic++){
    __syncthreads();
    for (int e=tid; e<800; e+=256){
      int n = e>>4, seg = (e&15)*4;
      *(float4*)&bufB[n*64+seg] = *(const float4*)(h3 + (long)b*12800 + n*256 + ic*64 + seg);
    }
    __syncthreads();
    for (int i=0;i<64;i+=4){
      float w0 = Wc1[(long)(ic*64+i+0)*128 + j];
      float w1 = Wc1[(long)(ic*64+i+1)*128 + j];
      float w2 = Wc1[(long)(ic*64+i+2)*128 + j];
      float w3 = Wc1[(long)(ic*64+i+3)*128 + j];
      #pragma unroll
      for (int q=0;q<25;q++){
        float4 xv = *(const float4*)&bufB[(nh*25+q)*64 + i];
        acc[q] += xv.x*w0 + xv.y*w1 + xv.z*w2 + xv.w*w3;
      }
    }
  }
  __syncthreads();
  #pragma unroll
  for (int q=0;q<25;q++) bufA[(nh*25+q)*128 + j] = acc[q];
  __syncthreads();
  {
    float a2[25];
    float bv = bc1[j];
    #pragma unroll
    for (int q=0;q<25;q++) a2[q]=bv;
    for (int qq=0; qq<50; qq++){
      float hvv = bufA[qq*128 + j];
      #pragma unroll
      for (int q=0;q<25;q++) a2[q] += adj[(nh*25+q)*50 + qq]*hvv;
    }
    __syncthreads();
    #pragma unroll
    for (int q=0;q<25;q++) bufB[(nh*25+q)*128 + j] = lrelu(a2[q]);
  }
  __syncthreads();
  {
    float a2[25];
    #pragma unroll
    for (int q=0;q<25;q++) a2[q]=0.f;
    for (int i=0;i<128;i+=4){
      float w0 = Wc2[(long)(i+0)*128 + j];
      float w1 = Wc2[(long)(i+1)*128 + j];
      float w2 = Wc2[(long)(i+2)*128 + j];
      float w3 = Wc2[(long)(i+3)*128 + j];
      #pragma unroll
      for (int q=0;q<25;q++){
        float4 xv = *(const float4*)&bufB[(nh*25+q)*128 + i];
        a2[q] += xv.x*w0 + xv.y*w1 + xv.z*w2 + xv.w*w3;
      }
    }
    __syncthreads();
    #pragma unroll
    for (int q=0;q<25;q++) bufA[(nh*25+q)*128 + j] = a2[q];
  }
  __syncthreads();
  {
    float a2[25];
    float bv = bc2[j];
    #pragma unroll
    for (int q=0;q<25;q++) a2[q]=bv;
    for (int qq=0; qq<50; qq++){
      float hvv = bufA[qq*128 + j];
      #pragma unroll
      for (int q=0;q<25;q++) a2[q] += adj[(nh*25+q)*50 + qq]*hvv;
    }
    __syncthreads();
    #pragma unroll
    for (int q=0;q<25;q++) bufB[(nh*25+q)*128 + j] = lrelu(a2[q]);
  }
  __syncthreads();
  if (tid < 128){
    float s = 0.f;
    for (int n=0;n<50;n++) s += bufB[n*128 + tid];
    xm[tid] = s * (1.f/50.f);
  }
  __syncthreads();
  if (tid < 64){
    float s = bf1[tid];
    for (int i=0;i<128;i++) s += xm[i]*Wf1[i*64 + tid];
    hv1[tid] = lrelu(s);
  }
  __syncthreads();
  if (tid < 80){
    float s = bf2[tid];
    for (int i=0;i<64;i++) s += hv1[i]*Wf2[i*80 + tid];
    raw[tid] = s;
  }
  __syncthreads();
  if (tid < 4){
    float c = 0.f;
    for (int k=0;k<20;k++){
      c += raw[k*4 + tid];
      hypg[b*80 + k*4 + tid] = maxp[tid] / (1.f + expf(-c));
    }
  }
}

// ---------------- scan: split-K z = AtA[p] @ y + fused y-update (XCD-swizzled grid) ----------------
// 1D grid 1600 blocks. swz = (bid%8)*200 + bid/8 -> p = swz/32, ytile = swz%32.
// Each XCD owns a contiguous p-range; all 32 y-blocks of a p co-resident on one XCD.
__global__ __launch_bounds__(256, 6) void k_z(const unsigned short* __restrict__ ata,
      const unsigned short* __restrict__ ybin, const float* __restrict__ ebuf,
      const float* __restrict__ hypg, int k,
      unsigned short* __restrict__ ybout, float* __restrict__ yout){
  const int bid = blockIdx.x;
  const int swz = (bid & 7)*200 + (bid >> 3);
  const int p   = swz >> 5;            // 0..49
  const int yt  = swz & 31;            // 0..31
  const int tid = threadIdx.x, wave = tid>>6, lane = tid&63;
  const int lr = lane&15, kg = lane>>4;
  const int tl = wave>>1;                        // tile local 0..1
  const int kh = wave&1;                         // K-half
  const int t  = yt*2 + tl;                      // n-tile 0..63
  const int n0 = t*16;
  __shared__ float part[2][16][17];
  const unsigned short* bp  = ata + ((long)p<<20) + (long)t*16384 + kh*8192 + lr*32 + kg*8;
  const unsigned short* ypg = ybin + ((long)lr*NP + p)*NN + kh*512 + kg*8;

  // epilogue operand preload (low-half waves only; overlaps MFMA)
  float yv4[4], e4[4];
  float4 hp4[4];
  if (kh == 0){
    #pragma unroll
    for (int r=0;r<4;r++){
      const int b = kg*4 + r;
      const long idx = ((long)b*NP + p)*NN + n0 + lr;
      yv4[r] = bfu(ybin[idx]); e4[r] = ebuf[idx];
      hp4[r] = *(const float4*)(hypg + b*80 + k*4);
    }
  }

  f32x4 a0={0.f,0.f,0.f,0.f}, a1={0.f,0.f,0.f,0.f}, a2={0.f,0.f,0.f,0.f}, a3={0.f,0.f,0.f,0.f};
  #pragma unroll
  for (int i=0;i<4;i++){
    bf16x8 b0 = *(const bf16x8*)(bp + (i*4+0)*512);
    bf16x8 b1 = *(const bf16x8*)(bp + (i*4+1)*512);
    bf16x8 b2 = *(const bf16x8*)(bp + (i*4+2)*512);
    bf16x8 b3 = *(const bf16x8*)(bp + (i*4+3)*512);
    bf16x8 q0 = *(const bf16x8*)(ypg + (i*4+0)*32);
    bf16x8 q1 = *(const bf16x8*)(ypg + (i*4+1)*32);
    bf16x8 q2 = *(const bf16x8*)(ypg + (i*4+2)*32);
    bf16x8 q3 = *(const bf16x8*)(ypg + (i*4+3)*32);
    a0 = __builtin_amdgcn_mfma_f32_16x16x32_bf16(q0, b0, a0, 0,0,0);
    a1 = __builtin_amdgcn_mfma_f32_16x16x32_bf16(q1, b1, a1, 0,0,0);
    a2 = __builtin_amdgcn_mfma_f32_16x16x32_bf16(q2, b2, a2, 0,0,0);
    a3 = __builtin_amdgcn_mfma_f32_16x16x32_bf16(q3, b3, a3, 0,0,0);
  }
  f32x4 zh = (a0 + a1) + (a2 + a3);
  if (kh == 1){
    #pragma unroll
    for (int r=0;r<4;r++) part[tl][kg*4+r][lr] = zh[r];
  }
  __syncthreads();
  if (kh == 0){
    #pragma unroll
    for (int r=0;r<4;r++){
      const int b = kg*4 + r;
      const long idx = ((long)b*NP + p)*NN + n0 + lr;
      float z = zh[r] + part[tl][kg*4+r][lr];
      float yv = yv4[r];
      float g = z + ((yv>0.f)?1.f:((yv<0.f)?-1.f:0.f))*hp4[r].y + e4[r];
      float ynv = yv - hp4[r].x*g;
      ybout[idx] = f2bf(ynv); yout[(long)k*YSZ + idx] = ynv;
    }
  }
}

// ---------------- scan: dl = Dm @ y_{k+1} (bf16) ; w += dl*eta*snb ; e = w + dl*rho_{k+1} ----------------
__global__ __launch_bounds__(256) void k_dm(const float* __restrict__ dmg,
      const float* __restrict__ snbg, const float* __restrict__ hypg, int k,
      const unsigned short* __restrict__ ybf, float* __restrict__ w, float* __restrict__ e){
  const int b = blockIdx.x, n0 = blockIdx.y*64, tid = threadIdx.x;
  __shared__ float ys[50][64];
  __shared__ float dms[2500];
  for (int i=tid;i<2500;i+=256) dms[i] = dmg[b*2500+i];
  for (int i=tid; i<3200; i+=256){
    int p=i>>6, nn=i&63;
    ys[p][nn] = bfu(ybf[((long)b*NP+p)*NN + n0 + nn]);
  }
  __syncthreads();
  const float eta = hypg[b*80 + k*4 + 3];
  const float rhon = hypg[b*80 + (k+1)*4 + 2];
  for (int i=tid; i<3200; i+=256){
    int p=i>>6, nn=i&63;
    float s=0.f;
    #pragma unroll 10
    for (int q=0;q<NP;q++) s += dms[p*50+q]*ys[q][nn];
    long idx = ((long)b*NP+p)*NN + n0 + nn;
    float wn = w[idx] + s*eta*snbg[b*NP+p];
    w[idx] = wn;
    e[idx] = wn + s*rhon;
  }
}

extern "C" void kernel_launch(void* const* d_in, const int* in_sizes, int n_in,
                              void* d_out, int out_size, void* d_ws, size_t ws_size,
                              hipStream_t stream){
  (void)in_sizes; (void)n_in; (void)out_size; (void)ws_size;
  const float* bin = (const float*)d_in[0];
  const float* A   = (const float*)d_in[1];
  const int*   ei  = (const int*)d_in[2];
  const float* mxp = (const float*)d_in[3];
  const float* We1 = (const float*)d_in[4];  const float* be1 = (const float*)d_in[5];
  const float* We2 = (const float*)d_in[6];  const float* be2 = (const float*)d_in[7];
  const float* We3 = (const float*)d_in[8];  const float* be3 = (const float*)d_in[9];
  const float* Wc1 = (const float*)d_in[10]; const float* bc1 = (const float*)d_in[11];
  const float* Wc2 = (const float*)d_in[12]; const float* bc2 = (const float*)d_in[13];
  const float* Wf1 = (const float*)d_in[14]; const float* bf1 = (const float*)d_in[15];
  const float* Wf2 = (const float*)d_in[16]; const float* bf2 = (const float*)d_in[17];
  const float* y0  = (const float*)d_in[18];
  const float* u0  = (const float*)d_in[19];
  const float* dd0 = (const float*)d_in[20];
  float* out = (float*)d_out;

  char* cur = (char*)d_ws;
  auto alloc = [&](size_t bytes)->void*{
    void* pp = (void*)cur; cur += (bytes + 255) & ~(size_t)255; return pp;
  };
  unsigned short* abfT = (unsigned short*)alloc(ASZ*2);              // 52.4 MB
  unsigned short* ata  = (unsigned short*)alloc((size_t)NP*1024*1024*2);  // 104.9 MB (tiled)
  float* atb = (float*)alloc(YSZ*4);
  unsigned short* ybf0 = (unsigned short*)alloc(YSZ*2);
  unsigned short* ybf1 = (unsigned short*)alloc(YSZ*2);
  float* w   = (float*)alloc(YSZ*4);
  float* eb  = (float*)alloc(YSZ*4);
  float* h1  = (float*)alloc((size_t)16*3200*4);
  float* h2  = (float*)alloc((size_t)16*6400*4);
  float* h3  = (float*)alloc((size_t)16*12800*4);
  float* adj = (float*)alloc((size_t)16*2500*4);
  float* dm  = (float*)alloc((size_t)16*2500*4);
  float* snb = (float*)alloc((size_t)16*50*4);
  float* hyp = (float*)alloc((size_t)16*80*4);
  float* part= (float*)alloc((size_t)84000000);

  // ---- one-time prep ----
  k_prep<<<dim3(50,8,16), dim3(256), 0, stream>>>(A, abfT);
  k_init<<<dim3(800), dim3(256), 0, stream>>>(y0, ybf0, (int)YSZ);

  // ---- merged: enc-L1 || AtA || Atb || graph (contiguous roles) ----
  k_big<<<dim3(2616), dim3(256), 0, stream>>>(abfT, ata, bin, We1, part, atb,
                                              ei, adj, dm, snb);
  k_enc_reduce<<<dim3(200), dim3(256), 0, stream>>>(part, be1, h1, 3200, 100);

  // ---- encoder L2/L3 ----
  k_enc2<<<dim3(7,100),  dim3(256), 0, stream>>>(h1, We2, part, 3200, 6400, 32, 1);
  k_enc_reduce<<<dim3(400), dim3(256), 0, stream>>>(part, be2, h2, 6400, 100);
  k_enc2<<<dim3(13,100), dim3(256), 0, stream>>>(h2, We3, part, 6400, 12800, 64, 1);
  k_enc_reduce<<<dim3(800), dim3(256), 0, stream>>>(part, be3, h3, 12800, 100);

  // ---- GNN/head + e0 ----
  k_gnn<<<dim3(16), dim3(256), 0, stream>>>(h3, Wc1, bc1, Wc2, bc2, Wf1, bf1, Wf2, bf2, mxp, adj, hyp);
  k_e0<<<dim3(800), dim3(256), 0, stream>>>(u0, dd0, atb, snb, hyp, w, eb);

  // ---- scan: 2 kernels/step (k_dm skipped on last step) ----
  for (int k=0;k<NK;k++){
    const unsigned short* ybin = (k & 1) ? ybf1 : ybf0;
    unsigned short* ybout      = (k & 1) ? ybf0 : ybf1;
    k_z<<<dim3(1600), dim3(256), 0, stream>>>(ata, ybin, eb, hyp, k, ybout, out);
    if (k < NK-1){
      const unsigned short* ybnew = (k & 1) ? ybf0 : ybf1;
      k_dm<<<dim3(16,16), dim3(256), 0, stream>>>(dm, snb, hyp, k, ybnew, w, eb);
    }
  }
}